// Round 16
// baseline (63.566 us; speedup 1.0000x reference)
//
#include <hip/hip_runtime.h>
#include <hip/hip_bf16.h>

#define BB 8
#define HH 64
#define WW 64
#define DD 128
#define NH 4
#define HD 32
#define KS 7
#define TS 8
#define HALO 14   // TS + KS - 1

typedef __attribute__((ext_vector_type(8))) short short8v;   // 8 bf16
typedef __attribute__((ext_vector_type(4))) short short4v;   // 4 bf16
typedef __attribute__((ext_vector_type(4))) float f32x4;
typedef unsigned short bf16_t;

__device__ inline bf16_t f2bf(float f) {
  __hip_bfloat16 h = __float2bfloat16(f);
  return *reinterpret_cast<bf16_t*>(&h);
}

// ---------------------------------------------------------------------------
// GEMM #1 v3 (R14): qkv.  64-row A-tiles (grid 512x3), B LDS-staged from
// fp32 weights (convert_w reverted: its extra launch cost more than halved
// B bytes saved).  LDS = 48 KB -> 3 blocks/CU.
// ABLATION NOTE: launched 3x this round (pure function of x,w,b -> idempotent).
// R16_dur - R14_dur(41.1) = 2*(qkv + launch).
// ---------------------------------------------------------------------------
__global__ __launch_bounds__(256) void qkv_mfma(
    const float* __restrict__ x, const float* __restrict__ w,
    const float* __restrict__ bqkv,
    bf16_t* __restrict__ q, bf16_t* __restrict__ k, bf16_t* __restrict__ v) {
  __shared__ __align__(16) short smA[64 * 128];    // 16 KB, reused as C
  __shared__ __align__(16) short smB[128 * 128];   // 32 KB
  const int tid = threadIdx.x;
  const int m_tile = blockIdx.x;   // 0..511 (64-row tiles)
  const int n_tile = blockIdx.y;   // 0..2  (0=q 1=k 2=v)

  const float* Ab = x + (size_t)m_tile * 64 * 128;
  const float* Bb = w + (size_t)n_tile * 128 * 128;
#pragma unroll
  for (int i = 0; i < 4; i++) {
    int idx = tid + i * 256;      // 0..1023: 64 rows x 16 chunks
    int r = idx >> 4, p = idx & 15;
    const float* ap = Ab + r * 128 + p * 8;
    float4 a0 = *(const float4*)ap;
    float4 a1 = *(const float4*)(ap + 4);
    short8v s;
    s[0] = f2bf(a0.x); s[1] = f2bf(a0.y); s[2] = f2bf(a0.z); s[3] = f2bf(a0.w);
    s[4] = f2bf(a1.x); s[5] = f2bf(a1.y); s[6] = f2bf(a1.z); s[7] = f2bf(a1.w);
    *(short8v*)((char*)smA + ((r * 256 + p * 16) ^ ((r & 7) << 4))) = s;
  }
#pragma unroll
  for (int i = 0; i < 8; i++) {
    int idx = tid + i * 256;      // 0..2047: 128 rows x 16 chunks
    int r = idx >> 4, p = idx & 15;
    const float* bp_ = Bb + r * 128 + p * 8;
    float4 b0 = *(const float4*)bp_;
    float4 b1 = *(const float4*)(bp_ + 4);
    short8v t;
    t[0] = f2bf(b0.x); t[1] = f2bf(b0.y); t[2] = f2bf(b0.z); t[3] = f2bf(b0.w);
    t[4] = f2bf(b1.x); t[5] = f2bf(b1.y); t[6] = f2bf(b1.z); t[7] = f2bf(b1.w);
    *(short8v*)((char*)smB + ((r * 256 + p * 16) ^ ((r & 7) << 4))) = t;
  }
  __syncthreads();

  const int lane = tid & 63, wid = tid >> 6;
  const int wm = wid >> 1, wn = wid & 1;
  const int l15 = lane & 15, l4 = lane >> 4;

  f32x4 acc[2][4] = {};
  const int rowA0 = wm * 32 + l15;
  const int rowB0 = wn * 64 + l15;
  const int swzA = (rowA0 & 7) << 4;
  const int swzB = (rowB0 & 7) << 4;

#pragma unroll
  for (int ks = 0; ks < 4; ks++) {
    const int cb = ks * 64 + l4 * 16;
    short8v a[2], b[4];
#pragma unroll
    for (int mi = 0; mi < 2; mi++)
      a[mi] = *(const short8v*)((const char*)smA +
                ((((rowA0 + mi * 16) * 256) + cb) ^ swzA));
#pragma unroll
    for (int nj = 0; nj < 4; nj++)
      b[nj] = *(const short8v*)((const char*)smB +
                ((((rowB0 + nj * 16) * 256) + cb) ^ swzB));
#pragma unroll
    for (int mi = 0; mi < 2; mi++)
#pragma unroll
      for (int nj = 0; nj < 4; nj++)
        acc[mi][nj] = __builtin_amdgcn_mfma_f32_16x16x32_bf16(a[mi], b[nj], acc[mi][nj], 0, 0, 0);
  }

  // ---- epilogue: bias+scale -> bf16 C-tile (overlays smA) -> coalesced out
  __syncthreads();
  short* smC = smA;   // [64 m][128 n] bf16, swz ((m&7)<<4)
  const float qscale = 0.17677669529663687f;  // 1/sqrt(32)
  const float sc = (n_tile == 0) ? qscale : 1.f;
#pragma unroll
  for (int nj = 0; nj < 4; nj++) {
    const int n_local = wn * 64 + nj * 16 + l15;
    const float bias = bqkv[n_tile * 128 + n_local];
#pragma unroll
    for (int mi = 0; mi < 2; mi++) {
#pragma unroll
      for (int r = 0; r < 4; r++) {
        const int m = wm * 32 + mi * 16 + l4 * 4 + r;
        *(bf16_t*)((char*)smC + ((m * 256 + n_local * 2) ^ ((m & 7) << 4))) =
            f2bf((acc[mi][nj][r] + bias) * sc);
      }
    }
  }
  __syncthreads();

  const int bblk = m_tile >> 6;    // 64 tiles of 64 rows per batch
  bf16_t* outp = (n_tile == 0) ? q : ((n_tile == 1) ? k : v);
#pragma unroll
  for (int i = 0; i < 4; i++) {
    const int idx = i * 256 + tid;         // 0..1023
    const int h = idx >> 8;                // head plane 0..3
    const int rem = idx & 255;
    const int m = rem >> 2, c = rem & 3;   // pixel row (0..63), 16B chunk
    short8v t8 = *(const short8v*)((const char*)smC +
        ((m * 256 + h * 64 + c * 16) ^ ((m & 7) << 4)));
    const int pix = (m_tile * 64 + m) & 4095;
    *(short8v*)(outp + ((size_t)(bblk * 4 + h)) * 131072 + (size_t)pix * 32 + c * 8) = t8;
  }
}

// ---------------------------------------------------------------------------
// Kernel 2: MFMA neighborhood attention, K-LDS-free (unchanged from R14).
// ---------------------------------------------------------------------------
__global__ __launch_bounds__(256) void attn_mfma(
    const bf16_t* __restrict__ q, const bf16_t* __restrict__ k,
    const bf16_t* __restrict__ v, bf16_t* __restrict__ ao) {
  // vtb: [32 d][512 B]  swz ((d&7)<<4), cols = 224 pos + 32 pad
  __shared__ __align__(16) char vtb[16384];

  const int tile = blockIdx.x;
  const int tx = tile >> 3, ty = tile & 7;
  const int head = blockIdx.y, bb = blockIdx.z;
  const size_t bh = ((size_t)bb * NH + head) * 4096;
  const bf16_t* kb = k + bh * HD;
  const bf16_t* vb = v + bh * HD;
  const bf16_t* qb = q + bh * HD;
  const int rstart = min(max(tx * TS - 3, 0), HH - HALO);
  const int cstart = min(max(ty * TS - 3, 0), WW - HALO);
  const int tid = threadIdx.x;
  const int lane = tid & 63, wid = tid >> 6;
  const int l15 = lane & 15, h4 = lane >> 4;

  short8v qf;
  int qx, qy;
  {
    const int pit = wid * 16 + l15;
    qx = tx * TS + (pit >> 3);
    qy = ty * TS + (pit & 7);
    qf = *(const short8v*)(qb + ((size_t)(qx * WW + qy)) * HD + h4 * 8);
  }
  const int wx0 = min(max(qx - 3, 0), HH - KS) - rstart;
  const int wy0 = min(max(qy - 3, 0), WW - KS) - cstart;

  const int x0 = tx * TS + wid * 2;
  const int w0 = min(max(x0 - 3, 0), HH - KS) - rstart;
  const int base = min(w0 & ~1, 4);

  short4v vl[4][2];
#pragma unroll
  for (int t = 0; t < 4; t++) {
    const int idx = tid + t * 256;
    if (idx < 784) {
      const int pp = idx >> 3, c = idx & 7;
      const int pr = pp / 7, pc2 = (pp % 7) * 2;
      const size_t g = ((size_t)((rstart + pr) * WW + (cstart + pc2))) * HD + c * 4;
      vl[t][0] = *(const short4v*)(vb + g);
      vl[t][1] = *(const short4v*)(vb + g + HD);
    }
  }

  f32x4 acc[10];
  const f32x4 zf = {0.f, 0.f, 0.f, 0.f};
  const int kcol = cstart + min(l15, 13);
#pragma unroll
  for (int ch = 0; ch < 2; ch++) {
    short8v kf[5];
#pragma unroll
    for (int i = 0; i < 5; i++) {
      const int pr = rstart + base + ch * 5 + i;
      kf[i] = *(const short8v*)(kb + ((size_t)(pr * WW + kcol)) * HD + h4 * 8);
    }
    __builtin_amdgcn_s_setprio(1);
#pragma unroll
    for (int i = 0; i < 5; i++)
      acc[ch * 5 + i] = __builtin_amdgcn_mfma_f32_16x16x32_bf16(kf[i], qf, zf, 0, 0, 0);
    __builtin_amdgcn_s_setprio(0);
  }

#pragma unroll
  for (int t = 0; t < 4; t++) {
    const int idx = tid + t * 256;
    if (idx < 784) {
      const int pp = idx >> 3, c = idx & 7;
      const int pr = pp / 7, pc2 = (pp % 7) * 2;
      const int pos0 = ((pr >> 1) << 5) + ((pc2 >> 2) << 3) + ((pr & 1) << 2) + (pc2 & 3);
#pragma unroll
      for (int j = 0; j < 4; j++) {
        const int d = c * 4 + j;
        const unsigned pk2 = (unsigned)(unsigned short)vl[t][0][j] |
                             ((unsigned)(unsigned short)vl[t][1][j] << 16);
        *(unsigned*)(vtb + ((d * 512 + pos0 * 2) ^ ((d & 7) << 4))) = pk2;
      }
    }
  }
  for (int idx = tid; idx < 512; idx += 256) {
    const int d = idx >> 4, pr = idx & 15;
    if (pr < 14) {
      const int pos = ((pr >> 1) << 5) + 24 + ((pr & 1) << 2) + 2;
      *(unsigned*)(vtb + ((d * 512 + pos * 2) ^ ((d & 7) << 4))) = 0u;
    }
  }
  __syncthreads();

  bool cv[4];
#pragma unroll
  for (int r = 0; r < 4; r++) cv[r] = ((unsigned)(h4 * 4 + r - wy0) < 7u);
  float sum = 0.f;
#pragma unroll
  for (int nt = 0; nt < 10; nt++) {
    const bool rv = ((unsigned)(base + nt - wx0) < 7u);
#pragma unroll
    for (int r = 0; r < 4; r++) {
      const float p = (rv && cv[r]) ? __expf(acc[nt][r]) : 0.f;
      acc[nt][r] = p;
      sum += p;
    }
  }
  sum += __shfl_xor(sum, 16);
  sum += __shfl_xor(sum, 32);
  const float inv = 1.f / sum;

  f32x4 o0 = zf, o1 = zf;
  const int swzv = (l15 & 7) << 4;
  const int cbase = (base >> 1) * 64;
  __builtin_amdgcn_s_setprio(1);
#pragma unroll
  for (int kc = 0; kc < 5; kc++) {
    union { unsigned u[4]; short8v s; } pa;
    pa.u[0] = (unsigned)f2bf(acc[2 * kc][0] * inv) |
              ((unsigned)f2bf(acc[2 * kc][1] * inv) << 16);
    pa.u[1] = (unsigned)f2bf(acc[2 * kc][2] * inv) |
              ((unsigned)f2bf(acc[2 * kc][3] * inv) << 16);
    pa.u[2] = (unsigned)f2bf(acc[2 * kc + 1][0] * inv) |
              ((unsigned)f2bf(acc[2 * kc + 1][1] * inv) << 16);
    pa.u[3] = (unsigned)f2bf(acc[2 * kc + 1][2] * inv) |
              ((unsigned)f2bf(acc[2 * kc + 1][3] * inv) << 16);
    const int boff = cbase + kc * 64 + h4 * 16;
    short8v vb0 = *(const short8v*)(vtb + ((l15 * 512 + boff) ^ swzv));
    short8v vb1 = *(const short8v*)(vtb + (((l15 + 16) * 512 + boff) ^ swzv));
    o0 = __builtin_amdgcn_mfma_f32_16x16x32_bf16(pa.s, vb0, o0, 0, 0, 0);
    o1 = __builtin_amdgcn_mfma_f32_16x16x32_bf16(pa.s, vb1, o1, 0, 0, 0);
  }
  __builtin_amdgcn_s_setprio(0);

#pragma unroll
  for (int r = 0; r < 4; r++) {
    const int pit = wid * 16 + h4 * 4 + r;
    const int x = tx * TS + (pit >> 3), y = ty * TS + (pit & 7);
    bf16_t* op = ao + ((size_t)bb * 4096 + x * WW + y) * DD + head * HD;
    op[l15]      = (bf16_t)f2bf(o0[r]);
    op[l15 + 16] = (bf16_t)f2bf(o1[r]);
  }
}

// ---------------------------------------------------------------------------
// GEMM #2 v3 (R14): proj.  64-row A-tiles (grid 512), B LDS-staged from
// fp32 weights.  LDS 48 KB -> 3 blocks/CU.
// ---------------------------------------------------------------------------
__global__ __launch_bounds__(256) void proj_mfma(
    const bf16_t* __restrict__ aob, const float* __restrict__ wp,
    const float* __restrict__ bp, float* __restrict__ out) {
  __shared__ __align__(16) char plds[49152];
  short* smA = (short*)plds;              // 16 KB [64][128] bf16
  short* smB = (short*)(plds + 16384);    // 32 KB [128][128] bf16; C overlays
  const int tid = threadIdx.x;
  const int m_tile = blockIdx.x;   // 0..511 (64-row tiles)

  const bf16_t* Ab = aob + (size_t)m_tile * 64 * 128;
#pragma unroll
  for (int i = 0; i < 4; i++) {
    int idx = tid + i * 256;      // 0..1023
    int r = idx >> 4, p = idx & 15;
    short8v s = *(const short8v*)(Ab + r * 128 + p * 8);
    *(short8v*)((char*)smA + ((r * 256 + p * 16) ^ ((r & 7) << 4))) = s;
  }
#pragma unroll
  for (int i = 0; i < 8; i++) {
    int idx = tid + i * 256;      // 0..2047
    int r = idx >> 4, p = idx & 15;
    const float* bp_ = wp + r * 128 + p * 8;
    float4 b0 = *(const float4*)bp_;
    float4 b1 = *(const float4*)(bp_ + 4);
    short8v t;
    t[0] = f2bf(b0.x); t[1] = f2bf(b0.y); t[2] = f2bf(b0.z); t[3] = f2bf(b0.w);
    t[4] = f2bf(b1.x); t[5] = f2bf(b1.y); t[6] = f2bf(b1.z); t[7] = f2bf(b1.w);
    *(short8v*)((char*)smB + ((r * 256 + p * 16) ^ ((r & 7) << 4))) = t;
  }
  __syncthreads();

  const int lane = tid & 63, wid = tid >> 6;
  const int wm = wid >> 1, wn = wid & 1;
  const int l15 = lane & 15, l4 = lane >> 4;

  f32x4 acc[2][4] = {};
  const int rowA0 = wm * 32 + l15;
  const int rowB0 = wn * 64 + l15;
  const int swzA = (rowA0 & 7) << 4;
  const int swzB = (rowB0 & 7) << 4;

#pragma unroll
  for (int ks = 0; ks < 4; ks++) {
    const int cb = ks * 64 + l4 * 16;
    short8v a[2], b[4];
#pragma unroll
    for (int mi = 0; mi < 2; mi++)
      a[mi] = *(const short8v*)((const char*)smA +
                ((((rowA0 + mi * 16) * 256) + cb) ^ swzA));
#pragma unroll
    for (int nj = 0; nj < 4; nj++)
      b[nj] = *(const short8v*)((const char*)smB +
                ((((rowB0 + nj * 16) * 256) + cb) ^ swzB));
#pragma unroll
    for (int mi = 0; mi < 2; mi++)
#pragma unroll
      for (int nj = 0; nj < 4; nj++)
        acc[mi][nj] = __builtin_amdgcn_mfma_f32_16x16x32_bf16(a[mi], b[nj], acc[mi][nj], 0, 0, 0);
  }

  // ---- epilogue: bias -> fp32 C-tile (overlays smB) -> coalesced float4
  __syncthreads();
  char* smC = plds + 16384;   // [64 m][512 B] fp32, swz ((m&7)<<5)
#pragma unroll
  for (int nj = 0; nj < 4; nj++) {
    const int n = wn * 64 + nj * 16 + l15;
    const float bias = bp[n];
#pragma unroll
    for (int mi = 0; mi < 2; mi++) {
#pragma unroll
      for (int r = 0; r < 4; r++) {
        const int m = wm * 32 + mi * 16 + l4 * 4 + r;
        *(float*)(smC + ((m * 512 + n * 4) ^ ((m & 7) << 5))) = acc[mi][nj][r] + bias;
      }
    }
  }
  __syncthreads();

#pragma unroll
  for (int i = 0; i < 8; i++) {
    const int idx = i * 256 + tid;         // 0..2047
    const int m = idx >> 5, c = idx & 31;  // row (0..63), float4 chunk
    float4 t = *(const float4*)(smC + ((m * 512 + c * 16) ^ ((m & 7) << 5)));
    *(float4*)(out + (size_t)(m_tile * 64 + m) * DD + c * 4) = t;
  }
}

// ---------------------------------------------------------------------------
extern "C" void kernel_launch(void* const* d_in, const int* in_sizes, int n_in,
                              void* d_out, int out_size, void* d_ws, size_t ws_size,
                              hipStream_t stream) {
  const float* x      = (const float*)d_in[0];
  const float* w_qkv  = (const float*)d_in[1];
  const float* b_qkv  = (const float*)d_in[2];
  const float* w_proj = (const float*)d_in[3];
  const float* b_proj = (const float*)d_in[4];
  float* out = (float*)d_out;

  const size_t per = (size_t)BB * NH * HH * WW * HD;  // 4,194,304 elements
  bf16_t* q  = (bf16_t*)d_ws;
  bf16_t* k  = q + per;
  bf16_t* v  = k + per;
  bf16_t* ao = v + per;   // 32 MB bf16 workspace

  // ABLATION (this round only): qkv launched 3x.  Pure function of
  // (x, w_qkv, b_qkv) fully overwriting q,k,v -> idempotent.
  // R16_dur - 41.1 = 2*(qkv + launch).
  qkv_mfma<<<dim3(512, 3), dim3(256), 0, stream>>>(x, w_qkv, b_qkv, q, k, v);
  qkv_mfma<<<dim3(512, 3), dim3(256), 0, stream>>>(x, w_qkv, b_qkv, q, k, v);
  qkv_mfma<<<dim3(512, 3), dim3(256), 0, stream>>>(x, w_qkv, b_qkv, q, k, v);
  attn_mfma<<<dim3(64, NH, BB), dim3(256), 0, stream>>>(q, k, v, ao);
  proj_mfma<<<dim3(512), dim3(256), 0, stream>>>(ao, w_proj, b_proj, out);
}

// Round 18
// 40.828 us; speedup vs baseline: 1.5569x; 1.5569x over previous
//
#include <hip/hip_runtime.h>
#include <hip/hip_bf16.h>

#define BB 8
#define HH 64
#define WW 64
#define DD 128
#define NH 4
#define HD 32
#define KS 7
#define TS 8
#define HALO 14   // TS + KS - 1

typedef __attribute__((ext_vector_type(8))) short short8v;   // 8 bf16
typedef __attribute__((ext_vector_type(4))) short short4v;   // 4 bf16
typedef __attribute__((ext_vector_type(4))) float f32x4;
typedef unsigned short bf16_t;

__device__ inline bf16_t f2bf(float f) {
  __hip_bfloat16 h = __float2bfloat16(f);
  return *reinterpret_cast<bf16_t*>(&h);
}

// ---------------------------------------------------------------------------
// GEMM #1 (R14, unchanged): qkv.  64-row A-tiles (grid 512x3), B LDS-staged.
// LDS = 48 KB -> 3 blocks/CU.
// ---------------------------------------------------------------------------
__global__ __launch_bounds__(256) void qkv_mfma(
    const float* __restrict__ x, const float* __restrict__ w,
    const float* __restrict__ bqkv,
    bf16_t* __restrict__ q, bf16_t* __restrict__ k, bf16_t* __restrict__ v) {
  __shared__ __align__(16) short smA[64 * 128];    // 16 KB, reused as C
  __shared__ __align__(16) short smB[128 * 128];   // 32 KB
  const int tid = threadIdx.x;
  const int m_tile = blockIdx.x;   // 0..511 (64-row tiles)
  const int n_tile = blockIdx.y;   // 0..2  (0=q 1=k 2=v)

  const float* Ab = x + (size_t)m_tile * 64 * 128;
  const float* Bb = w + (size_t)n_tile * 128 * 128;
#pragma unroll
  for (int i = 0; i < 4; i++) {
    int idx = tid + i * 256;
    int r = idx >> 4, p = idx & 15;
    const float* ap = Ab + r * 128 + p * 8;
    float4 a0 = *(const float4*)ap;
    float4 a1 = *(const float4*)(ap + 4);
    short8v s;
    s[0] = f2bf(a0.x); s[1] = f2bf(a0.y); s[2] = f2bf(a0.z); s[3] = f2bf(a0.w);
    s[4] = f2bf(a1.x); s[5] = f2bf(a1.y); s[6] = f2bf(a1.z); s[7] = f2bf(a1.w);
    *(short8v*)((char*)smA + ((r * 256 + p * 16) ^ ((r & 7) << 4))) = s;
  }
#pragma unroll
  for (int i = 0; i < 8; i++) {
    int idx = tid + i * 256;
    int r = idx >> 4, p = idx & 15;
    const float* bp_ = Bb + r * 128 + p * 8;
    float4 b0 = *(const float4*)bp_;
    float4 b1 = *(const float4*)(bp_ + 4);
    short8v t;
    t[0] = f2bf(b0.x); t[1] = f2bf(b0.y); t[2] = f2bf(b0.z); t[3] = f2bf(b0.w);
    t[4] = f2bf(b1.x); t[5] = f2bf(b1.y); t[6] = f2bf(b1.z); t[7] = f2bf(b1.w);
    *(short8v*)((char*)smB + ((r * 256 + p * 16) ^ ((r & 7) << 4))) = t;
  }
  __syncthreads();

  const int lane = tid & 63, wid = tid >> 6;
  const int wm = wid >> 1, wn = wid & 1;
  const int l15 = lane & 15, l4 = lane >> 4;

  f32x4 acc[2][4] = {};
  const int rowA0 = wm * 32 + l15;
  const int rowB0 = wn * 64 + l15;
  const int swzA = (rowA0 & 7) << 4;
  const int swzB = (rowB0 & 7) << 4;

#pragma unroll
  for (int ks = 0; ks < 4; ks++) {
    const int cb = ks * 64 + l4 * 16;
    short8v a[2], b[4];
#pragma unroll
    for (int mi = 0; mi < 2; mi++)
      a[mi] = *(const short8v*)((const char*)smA +
                ((((rowA0 + mi * 16) * 256) + cb) ^ swzA));
#pragma unroll
    for (int nj = 0; nj < 4; nj++)
      b[nj] = *(const short8v*)((const char*)smB +
                ((((rowB0 + nj * 16) * 256) + cb) ^ swzB));
#pragma unroll
    for (int mi = 0; mi < 2; mi++)
#pragma unroll
      for (int nj = 0; nj < 4; nj++)
        acc[mi][nj] = __builtin_amdgcn_mfma_f32_16x16x32_bf16(a[mi], b[nj], acc[mi][nj], 0, 0, 0);
  }

  __syncthreads();
  short* smC = smA;   // [64 m][128 n] bf16, swz ((m&7)<<4)
  const float qscale = 0.17677669529663687f;
  const float sc = (n_tile == 0) ? qscale : 1.f;
#pragma unroll
  for (int nj = 0; nj < 4; nj++) {
    const int n_local = wn * 64 + nj * 16 + l15;
    const float bias = bqkv[n_tile * 128 + n_local];
#pragma unroll
    for (int mi = 0; mi < 2; mi++) {
#pragma unroll
      for (int r = 0; r < 4; r++) {
        const int m = wm * 32 + mi * 16 + l4 * 4 + r;
        *(bf16_t*)((char*)smC + ((m * 256 + n_local * 2) ^ ((m & 7) << 4))) =
            f2bf((acc[mi][nj][r] + bias) * sc);
      }
    }
  }
  __syncthreads();

  const int bblk = m_tile >> 6;
  bf16_t* outp = (n_tile == 0) ? q : ((n_tile == 1) ? k : v);
#pragma unroll
  for (int i = 0; i < 4; i++) {
    const int idx = i * 256 + tid;
    const int h = idx >> 8;
    const int rem = idx & 255;
    const int m = rem >> 2, c = rem & 3;
    short8v t8 = *(const short8v*)((const char*)smC +
        ((m * 256 + h * 64 + c * 16) ^ ((m & 7) << 4)));
    const int pix = (m_tile * 64 + m) & 4095;
    *(short8v*)(outp + ((size_t)(bblk * 4 + h)) * 131072 + (size_t)pix * 32 + c * 8) = t8;
  }
}

// ---------------------------------------------------------------------------
// Kernel 2: fused attention (4 heads) + output projection.
// Block = (8x8 tile, batch); grid (64,8) = 512 blocks, fully resident.
// LDS 48 KB -> 3 blocks/CU:
//   [0,16K)  vtb: per-head V^T (reused x4); O-tile [64][128]bf16 overlays after
//   [16K,48K) wpb: w_proj bf16 staged once; fp32 C-tile overlays at the end
// Attn body identical to R14 attn_mfma (K streamed from global, P-in-regs).
// O never touches HBM: regs -> LDS -> proj MFMA (same bf16 bits as before).
// ---------------------------------------------------------------------------
__global__ __launch_bounds__(256) void attn_proj_fused(
    const bf16_t* __restrict__ q, const bf16_t* __restrict__ k,
    const bf16_t* __restrict__ v, const float* __restrict__ wp,
    const float* __restrict__ bpj, float* __restrict__ out) {
  __shared__ __align__(16) char lds[49152];
  char* vtb = lds;                       // 16 KB
  short* wpb = (short*)(lds + 16384);    // 32 KB

  const int tile = blockIdx.x;
  const int tx = tile >> 3, ty = tile & 7;
  const int bb = blockIdx.y;
  const int rstart = min(max(tx * TS - 3, 0), HH - HALO);
  const int cstart = min(max(ty * TS - 3, 0), WW - HALO);
  const int tid = threadIdx.x;
  const int lane = tid & 63, wid = tid >> 6;
  const int l15 = lane & 15, h4 = lane >> 4;
  const size_t bb4 = (size_t)bb * 4;

  // ---- stage w_proj once (fp32 -> bf16, swz ((r&7)<<4)); read after barriers
#pragma unroll
  for (int i = 0; i < 8; i++) {
    int idx = tid + i * 256;
    int r = idx >> 4, p = idx & 15;
    const float* bp_ = wp + r * 128 + p * 8;
    float4 b0 = *(const float4*)bp_;
    float4 b1 = *(const float4*)(bp_ + 4);
    short8v t;
    t[0] = f2bf(b0.x); t[1] = f2bf(b0.y); t[2] = f2bf(b0.z); t[3] = f2bf(b0.w);
    t[4] = f2bf(b1.x); t[5] = f2bf(b1.y); t[6] = f2bf(b1.z); t[7] = f2bf(b1.w);
    *(short8v*)((char*)wpb + ((r * 256 + p * 16) ^ ((r & 7) << 4))) = t;
  }

  // query coords / masks (head-independent)
  int qx, qy;
  {
    const int pit = wid * 16 + l15;
    qx = tx * TS + (pit >> 3);
    qy = ty * TS + (pit & 7);
  }
  const size_t qoff = (size_t)(qx * WW + qy) * HD + h4 * 8;
  const int wx0 = min(max(qx - 3, 0), HH - KS) - rstart;
  const int wy0 = min(max(qy - 3, 0), WW - KS) - cstart;
  const int x0 = tx * TS + wid * 2;
  const int w0 = min(max(x0 - 3, 0), HH - KS) - rstart;
  const int base = min(w0 & ~1, 4);
  bool cv[4];
#pragma unroll
  for (int r = 0; r < 4; r++) cv[r] = ((unsigned)(h4 * 4 + r - wy0) < 7u);
  const int kcol = cstart + min(l15, 13);
  const f32x4 zf = {0.f, 0.f, 0.f, 0.f};

  // preload Q fragments for all heads (latency hides under wpb staging)
  short8v qf[4];
#pragma unroll
  for (int h = 0; h < 4; h++)
    qf[h] = *(const short8v*)(q + (bb4 + h) * 131072 + qoff);

  unsigned oph[4][4];

#pragma unroll
  for (int h = 0; h < 4; h++) {
    const bf16_t* kb = k + (bb4 + h) * 131072;
    const bf16_t* vb = v + (bb4 + h) * 131072;

    // issue V loads (regs) before QK^T
    short4v vl[4][2];
#pragma unroll
    for (int t = 0; t < 4; t++) {
      const int idx = tid + t * 256;
      if (idx < 784) {
        const int pp = idx >> 3, c = idx & 7;
        const int pr = pp / 7, pc2 = (pp % 7) * 2;
        const size_t g = ((size_t)((rstart + pr) * WW + (cstart + pc2))) * HD + c * 4;
        vl[t][0] = *(const short4v*)(vb + g);
        vl[t][1] = *(const short4v*)(vb + g + HD);
      }
    }

    // S^T = K.Q^T, K streamed from global
    f32x4 acc[10];
#pragma unroll
    for (int ch = 0; ch < 2; ch++) {
      short8v kf[5];
#pragma unroll
      for (int i = 0; i < 5; i++) {
        const int pr = rstart + base + ch * 5 + i;
        kf[i] = *(const short8v*)(kb + ((size_t)(pr * WW + kcol)) * HD + h4 * 8);
      }
      __builtin_amdgcn_s_setprio(1);
#pragma unroll
      for (int i = 0; i < 5; i++)
        acc[ch * 5 + i] = __builtin_amdgcn_mfma_f32_16x16x32_bf16(kf[i], qf[h], zf, 0, 0, 0);
      __builtin_amdgcn_s_setprio(0);
    }

    // prev head's PV reads of vtb must finish before we overwrite it
    if (h > 0) __syncthreads();

    // pack + write V^T (pos remap); zero pad cols once (never overwritten)
#pragma unroll
    for (int t = 0; t < 4; t++) {
      const int idx = tid + t * 256;
      if (idx < 784) {
        const int pp = idx >> 3, c = idx & 7;
        const int pr = pp / 7, pc2 = (pp % 7) * 2;
        const int pos0 = ((pr >> 1) << 5) + ((pc2 >> 2) << 3) + ((pr & 1) << 2) + (pc2 & 3);
#pragma unroll
        for (int j = 0; j < 4; j++) {
          const int d = c * 4 + j;
          const unsigned pk2 = (unsigned)(unsigned short)vl[t][0][j] |
                               ((unsigned)(unsigned short)vl[t][1][j] << 16);
          *(unsigned*)(vtb + ((d * 512 + pos0 * 2) ^ ((d & 7) << 4))) = pk2;
        }
      }
    }
    if (h == 0) {
      for (int idx = tid; idx < 512; idx += 256) {
        const int d = idx >> 4, pr = idx & 15;
        if (pr < 14) {
          const int pos = ((pr >> 1) << 5) + 24 + ((pr & 1) << 2) + 2;
          *(unsigned*)(vtb + ((d * 512 + pos * 2) ^ ((d & 7) << 4))) = 0u;
        }
      }
    }
    __syncthreads();

    // mask + no-max softmax (regs)
    float sum = 0.f;
#pragma unroll
    for (int nt = 0; nt < 10; nt++) {
      const bool rv = ((unsigned)(base + nt - wx0) < 7u);
#pragma unroll
      for (int r = 0; r < 4; r++) {
        const float p = (rv && cv[r]) ? __expf(acc[nt][r]) : 0.f;
        acc[nt][r] = p;
        sum += p;
      }
    }
    sum += __shfl_xor(sum, 16);
    sum += __shfl_xor(sum, 32);
    const float inv = 1.f / sum;

    // O = P.V ; P normalized+packed in the loop
    f32x4 o0 = zf, o1 = zf;
    const int swzv = (l15 & 7) << 4;
    const int cbase = (base >> 1) * 64;
    __builtin_amdgcn_s_setprio(1);
#pragma unroll
    for (int kc = 0; kc < 5; kc++) {
      union { unsigned u[4]; short8v s; } pa;
      pa.u[0] = (unsigned)f2bf(acc[2 * kc][0] * inv) |
                ((unsigned)f2bf(acc[2 * kc][1] * inv) << 16);
      pa.u[1] = (unsigned)f2bf(acc[2 * kc][2] * inv) |
                ((unsigned)f2bf(acc[2 * kc][3] * inv) << 16);
      pa.u[2] = (unsigned)f2bf(acc[2 * kc + 1][0] * inv) |
                ((unsigned)f2bf(acc[2 * kc + 1][1] * inv) << 16);
      pa.u[3] = (unsigned)f2bf(acc[2 * kc + 1][2] * inv) |
                ((unsigned)f2bf(acc[2 * kc + 1][3] * inv) << 16);
      const int boff = cbase + kc * 64 + h4 * 16;
      short8v vb0 = *(const short8v*)(vtb + ((l15 * 512 + boff) ^ swzv));
      short8v vb1 = *(const short8v*)(vtb + (((l15 + 16) * 512 + boff) ^ swzv));
      o0 = __builtin_amdgcn_mfma_f32_16x16x32_bf16(pa.s, vb0, o0, 0, 0, 0);
      o1 = __builtin_amdgcn_mfma_f32_16x16x32_bf16(pa.s, vb1, o1, 0, 0, 0);
    }
    __builtin_amdgcn_s_setprio(0);

    oph[h][0] = (unsigned)f2bf(o0[0]) | ((unsigned)f2bf(o0[1]) << 16);
    oph[h][1] = (unsigned)f2bf(o0[2]) | ((unsigned)f2bf(o0[3]) << 16);
    oph[h][2] = (unsigned)f2bf(o1[0]) | ((unsigned)f2bf(o1[1]) << 16);
    oph[h][3] = (unsigned)f2bf(o1[2]) | ((unsigned)f2bf(o1[3]) << 16);
  }
  __syncthreads();   // last PV reads done -> overlay O-tile on vtb

  // ---- scatter O (bf16) -> A-tile [64 m][128 d], swz ((m&7)<<4)
#pragma unroll
  for (int h = 0; h < 4; h++) {
#pragma unroll
    for (int j = 0; j < 4; j++) {
      const unsigned u = oph[h][j];
      const int row0 = wid * 16 + h4 * 4 + (j & 1) * 2;   // q rows r=(j&1)*2, +1
      const int d = h * 32 + (j >> 1) * 16 + l15;
      *(bf16_t*)(vtb + ((row0 * 256 + d * 2) ^ ((row0 & 7) << 4))) = (bf16_t)(u & 0xFFFFu);
      const int row1 = row0 + 1;
      *(bf16_t*)(vtb + ((row1 * 256 + d * 2) ^ ((row1 & 7) << 4))) = (bf16_t)(u >> 16);
    }
  }
  __syncthreads();

  // ---- proj: C(64,128) = A @ wp^T   (R14 proj MFMA structure)
  const int wm = wid >> 1, wn = wid & 1;
  const int l4 = lane >> 4;
  f32x4 pacc[2][4] = {};
  const int rowA0 = wm * 32 + l15;
  const int rowB0 = wn * 64 + l15;
  const int swzA = (rowA0 & 7) << 4;
  const int swzB = (rowB0 & 7) << 4;

#pragma unroll
  for (int ks = 0; ks < 4; ks++) {
    const int cb = ks * 64 + l4 * 16;
    short8v a[2], b[4];
#pragma unroll
    for (int mi = 0; mi < 2; mi++)
      a[mi] = *(const short8v*)(vtb + ((((rowA0 + mi * 16) * 256) + cb) ^ swzA));
#pragma unroll
    for (int nj = 0; nj < 4; nj++)
      b[nj] = *(const short8v*)((const char*)wpb +
                ((((rowB0 + nj * 16) * 256) + cb) ^ swzB));
    __builtin_amdgcn_s_setprio(1);
#pragma unroll
    for (int mi = 0; mi < 2; mi++)
#pragma unroll
      for (int nj = 0; nj < 4; nj++)
        pacc[mi][nj] = __builtin_amdgcn_mfma_f32_16x16x32_bf16(a[mi], b[nj], pacc[mi][nj], 0, 0, 0);
    __builtin_amdgcn_s_setprio(0);
  }

  // ---- epilogue: bias -> fp32 C-tile (overlays wpb) -> coalesced float4
  __syncthreads();
  char* smC = lds + 16384;   // [64 m][512 B] fp32, swz ((m&7)<<5)
#pragma unroll
  for (int nj = 0; nj < 4; nj++) {
    const int n = wn * 64 + nj * 16 + l15;
    const float bias = bpj[n];
#pragma unroll
    for (int mi = 0; mi < 2; mi++) {
#pragma unroll
      for (int r = 0; r < 4; r++) {
        const int m = wm * 32 + mi * 16 + l4 * 4 + r;
        *(float*)(smC + ((m * 512 + n * 4) ^ ((m & 7) << 5))) = pacc[mi][nj][r] + bias;
      }
    }
  }
  __syncthreads();

  // writeout: in-tile row m=(px*8+py) -> global row bb*4096+(tx*8+px)*64+ty*8+py
  float* obase = out + ((size_t)bb * 4096 + (size_t)(tx * TS) * WW + ty * TS) * DD;
#pragma unroll
  for (int i = 0; i < 8; i++) {
    const int idx = i * 256 + tid;         // 0..2047
    const int m = idx >> 5, c = idx & 31;  // in-tile row, float4 chunk
    float4 t = *(const float4*)(smC + ((m * 512 + c * 16) ^ ((m & 7) << 5)));
    const size_t grow = (size_t)(m >> 3) * WW + (m & 7);
    *(float4*)(obase + grow * DD + c * 4) = t;
  }
}

// ---------------------------------------------------------------------------
extern "C" void kernel_launch(void* const* d_in, const int* in_sizes, int n_in,
                              void* d_out, int out_size, void* d_ws, size_t ws_size,
                              hipStream_t stream) {
  const float* x      = (const float*)d_in[0];
  const float* w_qkv  = (const float*)d_in[1];
  const float* b_qkv  = (const float*)d_in[2];
  const float* w_proj = (const float*)d_in[3];
  const float* b_proj = (const float*)d_in[4];
  float* out = (float*)d_out;

  const size_t per = (size_t)BB * NH * HH * WW * HD;  // 4,194,304 elements
  bf16_t* q = (bf16_t*)d_ws;
  bf16_t* k = q + per;
  bf16_t* v = k + per;    // 24 MB bf16 workspace

  qkv_mfma<<<dim3(512, 3), dim3(256), 0, stream>>>(x, w_qkv, b_qkv, q, k, v);
  attn_proj_fused<<<dim3(64, BB), dim3(256), 0, stream>>>(q, k, v, w_proj, b_proj, out);
}

// Round 19
// 40.454 us; speedup vs baseline: 1.5713x; 1.0093x over previous
//
#include <hip/hip_runtime.h>
#include <hip/hip_bf16.h>

#define BB 8
#define HH 64
#define WW 64
#define DD 128
#define NH 4
#define HD 32
#define KS 7
#define TS 8
#define HALO 14   // TS + KS - 1

typedef __attribute__((ext_vector_type(8))) short short8v;   // 8 bf16
typedef __attribute__((ext_vector_type(4))) short short4v;   // 4 bf16
typedef __attribute__((ext_vector_type(4))) float f32x4;
typedef unsigned short bf16_t;

__device__ inline bf16_t f2bf(float f) {
  __hip_bfloat16 h = __float2bfloat16(f);
  return *reinterpret_cast<bf16_t*>(&h);
}

// ---------------------------------------------------------------------------
// GEMM #1 (R14, unchanged): qkv.  64-row A-tiles (grid 512x3), B LDS-staged.
// LDS = 48 KB -> 3 blocks/CU.
// ---------------------------------------------------------------------------
__global__ __launch_bounds__(256) void qkv_mfma(
    const float* __restrict__ x, const float* __restrict__ w,
    const float* __restrict__ bqkv,
    bf16_t* __restrict__ q, bf16_t* __restrict__ k, bf16_t* __restrict__ v) {
  __shared__ __align__(16) short smA[64 * 128];    // 16 KB, reused as C
  __shared__ __align__(16) short smB[128 * 128];   // 32 KB
  const int tid = threadIdx.x;
  const int m_tile = blockIdx.x;   // 0..511 (64-row tiles)
  const int n_tile = blockIdx.y;   // 0..2  (0=q 1=k 2=v)

  const float* Ab = x + (size_t)m_tile * 64 * 128;
  const float* Bb = w + (size_t)n_tile * 128 * 128;
#pragma unroll
  for (int i = 0; i < 4; i++) {
    int idx = tid + i * 256;
    int r = idx >> 4, p = idx & 15;
    const float* ap = Ab + r * 128 + p * 8;
    float4 a0 = *(const float4*)ap;
    float4 a1 = *(const float4*)(ap + 4);
    short8v s;
    s[0] = f2bf(a0.x); s[1] = f2bf(a0.y); s[2] = f2bf(a0.z); s[3] = f2bf(a0.w);
    s[4] = f2bf(a1.x); s[5] = f2bf(a1.y); s[6] = f2bf(a1.z); s[7] = f2bf(a1.w);
    *(short8v*)((char*)smA + ((r * 256 + p * 16) ^ ((r & 7) << 4))) = s;
  }
#pragma unroll
  for (int i = 0; i < 8; i++) {
    int idx = tid + i * 256;
    int r = idx >> 4, p = idx & 15;
    const float* bp_ = Bb + r * 128 + p * 8;
    float4 b0 = *(const float4*)bp_;
    float4 b1 = *(const float4*)(bp_ + 4);
    short8v t;
    t[0] = f2bf(b0.x); t[1] = f2bf(b0.y); t[2] = f2bf(b0.z); t[3] = f2bf(b0.w);
    t[4] = f2bf(b1.x); t[5] = f2bf(b1.y); t[6] = f2bf(b1.z); t[7] = f2bf(b1.w);
    *(short8v*)((char*)smB + ((r * 256 + p * 16) ^ ((r & 7) << 4))) = t;
  }
  __syncthreads();

  const int lane = tid & 63, wid = tid >> 6;
  const int wm = wid >> 1, wn = wid & 1;
  const int l15 = lane & 15, l4 = lane >> 4;

  f32x4 acc[2][4] = {};
  const int rowA0 = wm * 32 + l15;
  const int rowB0 = wn * 64 + l15;
  const int swzA = (rowA0 & 7) << 4;
  const int swzB = (rowB0 & 7) << 4;

#pragma unroll
  for (int ks = 0; ks < 4; ks++) {
    const int cb = ks * 64 + l4 * 16;
    short8v a[2], b[4];
#pragma unroll
    for (int mi = 0; mi < 2; mi++)
      a[mi] = *(const short8v*)((const char*)smA +
                ((((rowA0 + mi * 16) * 256) + cb) ^ swzA));
#pragma unroll
    for (int nj = 0; nj < 4; nj++)
      b[nj] = *(const short8v*)((const char*)smB +
                ((((rowB0 + nj * 16) * 256) + cb) ^ swzB));
#pragma unroll
    for (int mi = 0; mi < 2; mi++)
#pragma unroll
      for (int nj = 0; nj < 4; nj++)
        acc[mi][nj] = __builtin_amdgcn_mfma_f32_16x16x32_bf16(a[mi], b[nj], acc[mi][nj], 0, 0, 0);
  }

  __syncthreads();
  short* smC = smA;   // [64 m][128 n] bf16, swz ((m&7)<<4)
  const float qscale = 0.17677669529663687f;
  const float sc = (n_tile == 0) ? qscale : 1.f;
#pragma unroll
  for (int nj = 0; nj < 4; nj++) {
    const int n_local = wn * 64 + nj * 16 + l15;
    const float bias = bqkv[n_tile * 128 + n_local];
#pragma unroll
    for (int mi = 0; mi < 2; mi++) {
#pragma unroll
      for (int r = 0; r < 4; r++) {
        const int m = wm * 32 + mi * 16 + l4 * 4 + r;
        *(bf16_t*)((char*)smC + ((m * 256 + n_local * 2) ^ ((m & 7) << 4))) =
            f2bf((acc[mi][nj][r] + bias) * sc);
      }
    }
  }
  __syncthreads();

  const int bblk = m_tile >> 6;
  bf16_t* outp = (n_tile == 0) ? q : ((n_tile == 1) ? k : v);
#pragma unroll
  for (int i = 0; i < 4; i++) {
    const int idx = i * 256 + tid;
    const int h = idx >> 8;
    const int rem = idx & 255;
    const int m = rem >> 2, c = rem & 3;
    short8v t8 = *(const short8v*)((const char*)smC +
        ((m * 256 + h * 64 + c * 16) ^ ((m & 7) << 4)));
    const int pix = (m_tile * 64 + m) & 4095;
    *(short8v*)(outp + ((size_t)(bblk * 4 + h)) * 131072 + (size_t)pix * 32 + c * 8) = t8;
  }
}

// ---------------------------------------------------------------------------
// Kernel 2: fused attention (4 heads) + projection, PIPELINED head loop.
// vs R18: (a) raw s_barrier + explicit lgkmcnt(0) in the head loop — LDS
// writes drain but global loads stay IN FLIGHT across barriers (the
// __syncthreads vmcnt(0) drain was serializing every head's prefetch);
// (b) V double-buffered one head ahead (vlb[2], static h&1 indexing);
// (c) softmax (reg-only) moved before barrier B to fill barrier skew.
// LDS 48 KB: vtb 16K (V^T per head, O-tile overlays) | wpb 32K (C overlays).
// ---------------------------------------------------------------------------
__global__ __launch_bounds__(256) void attn_proj_fused(
    const bf16_t* __restrict__ q, const bf16_t* __restrict__ k,
    const bf16_t* __restrict__ v, const float* __restrict__ wp,
    const float* __restrict__ bpj, float* __restrict__ out) {
  __shared__ __align__(16) char lds[49152];
  char* vtb = lds;                       // 16 KB
  short* wpb = (short*)(lds + 16384);    // 32 KB

  const int tile = blockIdx.x;
  const int tx = tile >> 3, ty = tile & 7;
  const int bb = blockIdx.y;
  const int rstart = min(max(tx * TS - 3, 0), HH - HALO);
  const int cstart = min(max(ty * TS - 3, 0), WW - HALO);
  const int tid = threadIdx.x;
  const int lane = tid & 63, wid = tid >> 6;
  const int l15 = lane & 15, h4 = lane >> 4;
  const size_t bb4 = (size_t)bb * 4;

  // ---- stage w_proj once (fp32 -> bf16, swz ((r&7)<<4))
#pragma unroll
  for (int i = 0; i < 8; i++) {
    int idx = tid + i * 256;
    int r = idx >> 4, p = idx & 15;
    const float* bp_ = wp + r * 128 + p * 8;
    float4 b0 = *(const float4*)bp_;
    float4 b1 = *(const float4*)(bp_ + 4);
    short8v t;
    t[0] = f2bf(b0.x); t[1] = f2bf(b0.y); t[2] = f2bf(b0.z); t[3] = f2bf(b0.w);
    t[4] = f2bf(b1.x); t[5] = f2bf(b1.y); t[6] = f2bf(b1.z); t[7] = f2bf(b1.w);
    *(short8v*)((char*)wpb + ((r * 256 + p * 16) ^ ((r & 7) << 4))) = t;
  }

  // query coords / masks (head-independent)
  int qx, qy;
  {
    const int pit = wid * 16 + l15;
    qx = tx * TS + (pit >> 3);
    qy = ty * TS + (pit & 7);
  }
  const size_t qoff = (size_t)(qx * WW + qy) * HD + h4 * 8;
  const int wx0 = min(max(qx - 3, 0), HH - KS) - rstart;
  const int wy0 = min(max(qy - 3, 0), WW - KS) - cstart;
  const int x0 = tx * TS + wid * 2;
  const int w0 = min(max(x0 - 3, 0), HH - KS) - rstart;
  const int base = min(w0 & ~1, 4);
  bool cv[4];
#pragma unroll
  for (int r = 0; r < 4; r++) cv[r] = ((unsigned)(h4 * 4 + r - wy0) < 7u);
  const int kcol = cstart + min(l15, 13);
  const f32x4 zf = {0.f, 0.f, 0.f, 0.f};

  // preload Q fragments for all heads
  short8v qf[4];
#pragma unroll
  for (int h = 0; h < 4; h++)
    qf[h] = *(const short8v*)(q + (bb4 + h) * 131072 + qoff);

  // V prefetch for head 0 (double buffer; static h&1 indexing under unroll)
  short4v vlb[2][4][2];
  {
    const bf16_t* vb0 = v + bb4 * 131072;
#pragma unroll
    for (int t = 0; t < 4; t++) {
      const int idx = tid + t * 256;
      if (idx < 784) {
        const int pp = idx >> 3, c = idx & 7;
        const int pr = pp / 7, pc2 = (pp % 7) * 2;
        const size_t g = ((size_t)((rstart + pr) * WW + (cstart + pc2))) * HD + c * 4;
        vlb[0][t][0] = *(const short4v*)(vb0 + g);
        vlb[0][t][1] = *(const short4v*)(vb0 + g + HD);
      }
    }
  }

  unsigned oph[4][4];

#pragma unroll
  for (int h = 0; h < 4; h++) {
    const bf16_t* kb = k + (bb4 + h) * 131072;

    // S^T = K.Q^T, K streamed from global
    f32x4 acc[10];
#pragma unroll
    for (int ch = 0; ch < 2; ch++) {
      short8v kf[5];
#pragma unroll
      for (int i = 0; i < 5; i++) {
        const int pr = rstart + base + ch * 5 + i;
        kf[i] = *(const short8v*)(kb + ((size_t)(pr * WW + kcol)) * HD + h4 * 8);
      }
      __builtin_amdgcn_s_setprio(1);
#pragma unroll
      for (int i = 0; i < 5; i++)
        acc[ch * 5 + i] = __builtin_amdgcn_mfma_f32_16x16x32_bf16(kf[i], qf[h], zf, 0, 0, 0);
      __builtin_amdgcn_s_setprio(0);
    }

    // barrier A: prev head's PV has consumed its vtb reads (waits precede its
    // MFMAs), so a raw barrier suffices — no vmcnt/lgkm drain needed.
    if (h > 0) {
      __builtin_amdgcn_sched_barrier(0);
      __builtin_amdgcn_s_barrier();
      __builtin_amdgcn_sched_barrier(0);
    }

    // pack + write V^T (pos remap) from vlb[h&1]
#pragma unroll
    for (int t = 0; t < 4; t++) {
      const int idx = tid + t * 256;
      if (idx < 784) {
        const int pp = idx >> 3, c = idx & 7;
        const int pr = pp / 7, pc2 = (pp % 7) * 2;
        const int pos0 = ((pr >> 1) << 5) + ((pc2 >> 2) << 3) + ((pr & 1) << 2) + (pc2 & 3);
#pragma unroll
        for (int j = 0; j < 4; j++) {
          const int d = c * 4 + j;
          const unsigned pk2 = (unsigned)(unsigned short)vlb[h & 1][t][0][j] |
                               ((unsigned)(unsigned short)vlb[h & 1][t][1][j] << 16);
          *(unsigned*)(vtb + ((d * 512 + pos0 * 2) ^ ((d & 7) << 4))) = pk2;
        }
      }
    }
    if (h == 0) {
      for (int idx = tid; idx < 512; idx += 256) {
        const int d = idx >> 4, pr = idx & 15;
        if (pr < 14) {
          const int pos = ((pr >> 1) << 5) + 24 + ((pr & 1) << 2) + 2;
          *(unsigned*)(vtb + ((d * 512 + pos * 2) ^ ((d & 7) << 4))) = 0u;
        }
      }
    }

    // prefetch next head's V — these global loads stay in flight across the
    // raw barrier below (only lgkmcnt is drained) and land at next pack.
    if (h < 3) {
      const bf16_t* vbn = v + (bb4 + h + 1) * 131072;
#pragma unroll
      for (int t = 0; t < 4; t++) {
        const int idx = tid + t * 256;
        if (idx < 784) {
          const int pp = idx >> 3, c = idx & 7;
          const int pr = pp / 7, pc2 = (pp % 7) * 2;
          const size_t g = ((size_t)((rstart + pr) * WW + (cstart + pc2))) * HD + c * 4;
          vlb[(h + 1) & 1][t][0] = *(const short4v*)(vbn + g);
          vlb[(h + 1) & 1][t][1] = *(const short4v*)(vbn + g + HD);
        }
      }
    }

    // softmax (register-only) — fills barrier skew / prefetch latency
    float sum = 0.f;
#pragma unroll
    for (int nt = 0; nt < 10; nt++) {
      const bool rv = ((unsigned)(base + nt - wx0) < 7u);
#pragma unroll
      for (int r = 0; r < 4; r++) {
        const float p = (rv && cv[r]) ? __expf(acc[nt][r]) : 0.f;
        acc[nt][r] = p;
        sum += p;
      }
    }
    sum += __shfl_xor(sum, 16);
    sum += __shfl_xor(sum, 32);
    const float inv = 1.f / sum;

    // barrier B: drain LDS writes (and shuffles) only; V prefetch keeps flying
    asm volatile("s_waitcnt lgkmcnt(0)" ::: "memory");
    __builtin_amdgcn_sched_barrier(0);
    __builtin_amdgcn_s_barrier();
    __builtin_amdgcn_sched_barrier(0);

    // O = P.V ; P normalized+packed in the loop
    f32x4 o0 = zf, o1 = zf;
    const int swzv = (l15 & 7) << 4;
    const int cbase = (base >> 1) * 64;
    __builtin_amdgcn_s_setprio(1);
#pragma unroll
    for (int kc = 0; kc < 5; kc++) {
      union { unsigned u[4]; short8v s; } pa;
      pa.u[0] = (unsigned)f2bf(acc[2 * kc][0] * inv) |
                ((unsigned)f2bf(acc[2 * kc][1] * inv) << 16);
      pa.u[1] = (unsigned)f2bf(acc[2 * kc][2] * inv) |
                ((unsigned)f2bf(acc[2 * kc][3] * inv) << 16);
      pa.u[2] = (unsigned)f2bf(acc[2 * kc + 1][0] * inv) |
                ((unsigned)f2bf(acc[2 * kc + 1][1] * inv) << 16);
      pa.u[3] = (unsigned)f2bf(acc[2 * kc + 1][2] * inv) |
                ((unsigned)f2bf(acc[2 * kc + 1][3] * inv) << 16);
      const int boff = cbase + kc * 64 + h4 * 16;
      short8v vb0 = *(const short8v*)(vtb + ((l15 * 512 + boff) ^ swzv));
      short8v vb1 = *(const short8v*)(vtb + (((l15 + 16) * 512 + boff) ^ swzv));
      o0 = __builtin_amdgcn_mfma_f32_16x16x32_bf16(pa.s, vb0, o0, 0, 0, 0);
      o1 = __builtin_amdgcn_mfma_f32_16x16x32_bf16(pa.s, vb1, o1, 0, 0, 0);
    }
    __builtin_amdgcn_s_setprio(0);

    oph[h][0] = (unsigned)f2bf(o0[0]) | ((unsigned)f2bf(o0[1]) << 16);
    oph[h][1] = (unsigned)f2bf(o0[2]) | ((unsigned)f2bf(o0[3]) << 16);
    oph[h][2] = (unsigned)f2bf(o1[0]) | ((unsigned)f2bf(o1[1]) << 16);
    oph[h][3] = (unsigned)f2bf(o1[2]) | ((unsigned)f2bf(o1[3]) << 16);
  }
  __syncthreads();   // last PV reads done -> overlay O-tile on vtb

  // ---- scatter O (bf16) -> A-tile [64 m][128 d], swz ((m&7)<<4)
#pragma unroll
  for (int h = 0; h < 4; h++) {
#pragma unroll
    for (int j = 0; j < 4; j++) {
      const unsigned u = oph[h][j];
      const int row0 = wid * 16 + h4 * 4 + (j & 1) * 2;
      const int d = h * 32 + (j >> 1) * 16 + l15;
      *(bf16_t*)(vtb + ((row0 * 256 + d * 2) ^ ((row0 & 7) << 4))) = (bf16_t)(u & 0xFFFFu);
      const int row1 = row0 + 1;
      *(bf16_t*)(vtb + ((row1 * 256 + d * 2) ^ ((row1 & 7) << 4))) = (bf16_t)(u >> 16);
    }
  }
  __syncthreads();

  // ---- proj: C(64,128) = A @ wp^T
  const int wm = wid >> 1, wn = wid & 1;
  const int l4 = lane >> 4;
  f32x4 pacc[2][4] = {};
  const int rowA0 = wm * 32 + l15;
  const int rowB0 = wn * 64 + l15;
  const int swzA = (rowA0 & 7) << 4;
  const int swzB = (rowB0 & 7) << 4;

#pragma unroll
  for (int ks = 0; ks < 4; ks++) {
    const int cb = ks * 64 + l4 * 16;
    short8v a[2], b[4];
#pragma unroll
    for (int mi = 0; mi < 2; mi++)
      a[mi] = *(const short8v*)(vtb + ((((rowA0 + mi * 16) * 256) + cb) ^ swzA));
#pragma unroll
    for (int nj = 0; nj < 4; nj++)
      b[nj] = *(const short8v*)((const char*)wpb +
                ((((rowB0 + nj * 16) * 256) + cb) ^ swzB));
    __builtin_amdgcn_s_setprio(1);
#pragma unroll
    for (int mi = 0; mi < 2; mi++)
#pragma unroll
      for (int nj = 0; nj < 4; nj++)
        pacc[mi][nj] = __builtin_amdgcn_mfma_f32_16x16x32_bf16(a[mi], b[nj], pacc[mi][nj], 0, 0, 0);
    __builtin_amdgcn_s_setprio(0);
  }

  // ---- epilogue: bias -> fp32 C-tile (overlays wpb) -> coalesced float4
  __syncthreads();
  char* smC = lds + 16384;   // [64 m][512 B] fp32, swz ((m&7)<<5)
#pragma unroll
  for (int nj = 0; nj < 4; nj++) {
    const int n = wn * 64 + nj * 16 + l15;
    const float bias = bpj[n];
#pragma unroll
    for (int mi = 0; mi < 2; mi++) {
#pragma unroll
      for (int r = 0; r < 4; r++) {
        const int m = wm * 32 + mi * 16 + l4 * 4 + r;
        *(float*)(smC + ((m * 512 + n * 4) ^ ((m & 7) << 5))) = pacc[mi][nj][r] + bias;
      }
    }
  }
  __syncthreads();

  float* obase = out + ((size_t)bb * 4096 + (size_t)(tx * TS) * WW + ty * TS) * DD;
#pragma unroll
  for (int i = 0; i < 8; i++) {
    const int idx = i * 256 + tid;
    const int m = idx >> 5, c = idx & 31;
    float4 t = *(const float4*)(smC + ((m * 512 + c * 16) ^ ((m & 7) << 5)));
    const size_t grow = (size_t)(m >> 3) * WW + (m & 7);
    *(float4*)(obase + grow * DD + c * 4) = t;
  }
}

// ---------------------------------------------------------------------------
extern "C" void kernel_launch(void* const* d_in, const int* in_sizes, int n_in,
                              void* d_out, int out_size, void* d_ws, size_t ws_size,
                              hipStream_t stream) {
  const float* x      = (const float*)d_in[0];
  const float* w_qkv  = (const float*)d_in[1];
  const float* b_qkv  = (const float*)d_in[2];
  const float* w_proj = (const float*)d_in[3];
  const float* b_proj = (const float*)d_in[4];
  float* out = (float*)d_out;

  const size_t per = (size_t)BB * NH * HH * WW * HD;  // 4,194,304 elements
  bf16_t* q = (bf16_t*)d_ws;
  bf16_t* k = q + per;
  bf16_t* v = k + per;    // 24 MB bf16 workspace

  qkv_mfma<<<dim3(512, 3), dim3(256), 0, stream>>>(x, w_qkv, b_qkv, q, k, v);
  attn_proj_fused<<<dim3(64, BB), dim3(256), 0, stream>>>(q, k, v, w_proj, b_proj, out);
}